// Round 9
// baseline (144.474 us; speedup 1.0000x reference)
//
#include <hip/hip_runtime.h>
#include <math.h>

#define K_N   30
#define N_OUT 1024
#define BB    4096
#define SMEM_BYTES 155648

typedef unsigned short ushort_t;
typedef __attribute__((ext_vector_type(8))) short bf16x8;
typedef __attribute__((ext_vector_type(4))) float f32x4;

#define GLOBAL_AS(p) ((const __attribute__((address_space(1))) void*)(p))
#define LDS_AS(p)    ((__attribute__((address_space(3))) void*)(p))

#define MFMA(a, b, c) (c) = __builtin_amdgcn_mfma_f32_16x16x32_bf16((a), (b), (c), 0, 0, 0)
#define MF3(ah, al, bh, bl, c) do { MFMA(ah, bh, c); MFMA(ah, bl, c); MFMA(al, bh, c); } while (0)

__device__ __forceinline__ ushort_t f2bf(float x) {
  union { float f; unsigned u; } a; a.f = x;
  unsigned r = a.u + 0x7FFFu + ((a.u >> 16) & 1u);
  return (ushort_t)(r >> 16);
}
__device__ __forceinline__ float bf2f(ushort_t h) {
  union { float f; unsigned u; } a; a.u = ((unsigned)h) << 16;
  return a.f;
}

__device__ __forceinline__ float choquet_one(float v0, float v1, float v2,
                                             float F0, float F1, float F2,
                                             float F3, float F4, float F5) {
  // stable descending argsort of (v0,v1,v2); ties -> lower index first
  bool c01 = v1 > v0, c02 = v2 > v0, c12 = v2 > v1;
  int r0 = (int)c01 + (int)c02;
  int r1 = (int)(!c01) + (int)c12;
  int p0 = (r0 == 0) ? 0 : ((r1 == 0) ? 1 : 2);
  int p1 = (r0 == 1) ? 0 : ((r1 == 1) ? 1 : 2);
  int p2 = 3 - p0 - p1;
  float sv0 = (p0 == 0) ? v0 : ((p0 == 1) ? v1 : v2);
  float sv1 = (p1 == 0) ? v0 : ((p1 == 1) ? v1 : v2);
  float sv2 = (p2 == 0) ? v0 : ((p2 == 1) ? v1 : v2);
  float fm0 = (p0 == 0) ? F0 : ((p0 == 1) ? F1 : F3);  // FM[2^p0-1]
  float fm1 = (p2 == 2) ? F2 : ((p2 == 1) ? F4 : F5);  // FM[2^p0+2^p1-1]
  return (sv0 - sv1) * fm0 + (sv1 - sv2) * fm1 + sv2;
}

// ---------------------------------------------------------------------------
// Launch 1: weight f32 -> bf16 hi/lo split. 832 x 512 covers 425984 exactly.
// ---------------------------------------------------------------------------
__global__ __launch_bounds__(512) void cicdm_split(
    const float* __restrict__ w1, const float* __restrict__ w2,
    const float* __restrict__ w3, ushort_t* __restrict__ w1h,
    ushort_t* __restrict__ w1l, ushort_t* __restrict__ w2h,
    ushort_t* __restrict__ w2l, ushort_t* __restrict__ w3h,
    ushort_t* __restrict__ w3l) {
  int i = blockIdx.x * 512 + threadIdx.x;
  float v;
  ushort_t *ph, *pl;
  int off;
  if (i < 262144) {            // w1: 256x1024
    off = i; v = w1[off]; ph = w1h; pl = w1l;
  } else if (i < 294912) {     // w2: 128x256
    off = i - 262144; v = w2[off]; ph = w2h; pl = w2l;
  } else {                     // w3: 1024x128
    off = i - 294912; v = w3[off]; ph = w3h; pl = w3l;
  }
  ushort_t h = f2bf(v);
  ph[off] = h;
  pl[off] = f2bf(v - bf2f(h));
}

// ---------------------------------------------------------------------------
// Launch 2: fully-fused row-local kernel. 256 blocks x 512 thr (8 waves),
// block owns rows [bid*16, bid*16+16). No grid sync; 3 block barriers.
// LDS map (155648 B dynamic):
//   sC  [2][16][1024] bf16 @0       (64 KB)  XOR-swizzled chunks
//   wq  8 waves x 8 KB     @65536   (64 KB)  wave-private W staging dbuf
//   sSel[16][32] f32       @65536   (overlaps wq; choquet phase only)
//   sH1 [2][16][256] bf16  @131072  (16 KB)
//   sH2 [2][16][128] bf16  @147456  ( 8 KB)
// W-fragments: per-lane global src -> linear LDS (identity frag layout),
// counted s_waitcnt vmcnt(N) keeps 1 k-step in flight (wave-local, no barrier).
// Split-bf16: acc += ah*wh + ah*wl + al*wh  (~2^-17 rel err).
// ---------------------------------------------------------------------------
__global__ __launch_bounds__(512, 2) void cicdm_fused(
    const int* __restrict__ stu_id, const int* __restrict__ q_idx,
    const float* __restrict__ emb, const float* __restrict__ fm_vars,
    const float* __restrict__ b1, const float* __restrict__ b2,
    const float* __restrict__ b3, const ushort_t* __restrict__ w1h,
    const ushort_t* __restrict__ w1l, const ushort_t* __restrict__ w2h,
    const ushort_t* __restrict__ w2l, const ushort_t* __restrict__ w3h,
    const ushort_t* __restrict__ w3l, float* __restrict__ out) {
  extern __shared__ __align__(16) char dsm[];
  ushort_t* sC = (ushort_t*)dsm;                  // hi @0, lo @+16384 (ushorts)
  ushort_t* wq = (ushort_t*)(dsm + 65536 + (threadIdx.x >> 6) * 8192);
  float* sSel = (float*)(dsm + 65536);
  ushort_t* sH1 = (ushort_t*)(dsm + 131072);      // hi @0, lo @+4096 (ushorts)
  ushort_t* sH2 = (ushort_t*)(dsm + 147456);      // hi @0, lo @+2048 (ushorts)

  const int bid = blockIdx.x, tid = threadIdx.x;
  const int lane = tid & 63, wid = tid >> 6;
  const int lrow = lane & 15, lc = lane >> 4;
  const int row0 = bid * 16;

  // ================= phase A: choquet -> sC =================
  if (tid < 16 * K_N) {
    int r = tid / K_N, c = tid % K_N;
    float x = emb[(size_t)stu_id[row0 + r] * K_N + c];
    sSel[r * 32 + c] = 1.f / (1.f + expf(-x));
  }
  __syncthreads();
  {
    const int n0 = tid * 2;
    const int qa0 = q_idx[n0 * 3 + 0], qa1 = q_idx[n0 * 3 + 1],
              qa2 = q_idx[n0 * 3 + 2];
    const int qb0 = q_idx[n0 * 3 + 3], qb1 = q_idx[n0 * 3 + 4],
              qb2 = q_idx[n0 * 3 + 5];
    float fa[6], fb[6];
#pragma unroll
    for (int v = 0; v < 6; ++v) {
      fa[v] = fabsf(fm_vars[v * N_OUT + n0]);
      fb[v] = fabsf(fm_vars[v * N_OUT + n0 + 1]);
    }
    float A0 = fminf(fa[0], 1.f), A1 = fminf(fa[1], 1.f), A3 = fminf(fa[3], 1.f);
    float A2 = fminf(fmaxf(fa[0], fa[1]) + fa[2], 1.f);
    float A4 = fminf(fmaxf(fa[3], fa[0]) + fa[4], 1.f);
    float A5 = fminf(fmaxf(fa[3], fa[1]) + fa[5], 1.f);
    float B0 = fminf(fb[0], 1.f), B1 = fminf(fb[1], 1.f), B3 = fminf(fb[3], 1.f);
    float B2 = fminf(fmaxf(fb[0], fb[1]) + fb[2], 1.f);
    float B4 = fminf(fmaxf(fb[3], fb[0]) + fb[4], 1.f);
    float B5 = fminf(fmaxf(fb[3], fb[1]) + fb[5], 1.f);
    const int kc = n0 >> 3, wi = n0 & 7;  // chunk + within (wi even)
#pragma unroll 4
    for (int r = 0; r < 16; ++r) {
      const float* sr = sSel + r * 32;
      float cA = choquet_one(sr[qa0], sr[qa1], sr[qa2], A0, A1, A2, A3, A4, A5);
      float cB = choquet_one(sr[qb0], sr[qb1], sr[qb2], B0, B1, B2, B3, B4, B5);
      ushort_t hA = f2bf(cA), hB = f2bf(cB);
      ushort_t lA = f2bf(cA - bf2f(hA)), lB = f2bf(cB - bf2f(hB));
      int byo = r * 2048 + ((kc ^ (r & 7)) * 8 + wi) * 2;
      *(unsigned*)((char*)sC + byo) = (unsigned)hA | ((unsigned)hB << 16);
      *(unsigned*)((char*)sC + 32768 + byo) = (unsigned)lA | ((unsigned)lB << 16);
    }
  }
  __syncthreads();

  // ================= phase B: GEMM1 (N=256, K=1024) =================
  {
    auto stage = [&](int cur, int kc) {
#pragma unroll
      for (int j = 0; j < 2; ++j) {
        int col = wid * 32 + j * 16 + lrow;
        const ushort_t* s0 = w1h + (size_t)col * 1024 + kc * 32 + lc * 8;
        const ushort_t* s1 = w1l + (size_t)col * 1024 + kc * 32 + lc * 8;
        __builtin_amdgcn_global_load_lds(GLOBAL_AS(s0),
            LDS_AS(wq + cur * 2048 + j * 1024), 16, 0, 0);
        __builtin_amdgcn_global_load_lds(GLOBAL_AS(s1),
            LDS_AS(wq + cur * 2048 + j * 1024 + 512), 16, 0, 0);
      }
    };
    f32x4 acc0 = {}, acc1 = {};
    stage(0, 0);
#pragma unroll 2
    for (int kc = 0; kc < 32; ++kc) {
      int cur = kc & 1;
      if (kc < 31) {
        stage(cur ^ 1, kc + 1);
        asm volatile("s_waitcnt vmcnt(4)" ::: "memory");
      } else {
        asm volatile("s_waitcnt vmcnt(0)" ::: "memory");
      }
      int pA = (kc * 4 + lc) ^ (lrow & 7);
      bf16x8 ah = *(const bf16x8*)(sC + lrow * 1024 + pA * 8);
      bf16x8 al = *(const bf16x8*)(sC + 16384 + lrow * 1024 + pA * 8);
      bf16x8 b0h = *(const bf16x8*)(wq + cur * 2048 + lane * 8);
      bf16x8 b0l = *(const bf16x8*)(wq + cur * 2048 + 512 + lane * 8);
      bf16x8 b1h = *(const bf16x8*)(wq + cur * 2048 + 1024 + lane * 8);
      bf16x8 b1l = *(const bf16x8*)(wq + cur * 2048 + 1536 + lane * 8);
      MF3(ah, al, b0h, b0l, acc0);
      MF3(ah, al, b1h, b1l, acc1);
    }
    // epilogue -> sH1 (relu, hi/lo, swizzled)
#pragma unroll
    for (int j = 0; j < 2; ++j) {
      f32x4 a = j ? acc1 : acc0;
      int col = wid * 32 + j * 16 + lrow;
      float bv = b1[col];
      int kc = col >> 3, wi = col & 7;
#pragma unroll
      for (int rr = 0; rr < 4; ++rr) {
        int r = lc * 4 + rr;
        float v = fmaxf(a[rr] + bv, 0.f);
        ushort_t h = f2bf(v);
        int byo = r * 512 + ((kc ^ (r & 7)) * 8 + wi) * 2;
        *(ushort_t*)((char*)sH1 + byo) = h;
        *(ushort_t*)((char*)sH1 + 8192 + byo) = f2bf(v - bf2f(h));
      }
    }
  }
  __syncthreads();

  // ================= phase C: GEMM2 (N=128, K=256) =================
  {
    auto stage = [&](int cur, int ks) {
      int col = wid * 16 + lrow;
      const ushort_t* s0 = w2h + (size_t)col * 256 + ks * 32 + lc * 8;
      const ushort_t* s1 = w2l + (size_t)col * 256 + ks * 32 + lc * 8;
      __builtin_amdgcn_global_load_lds(GLOBAL_AS(s0), LDS_AS(wq + cur * 2048),
                                       16, 0, 0);
      __builtin_amdgcn_global_load_lds(GLOBAL_AS(s1),
                                       LDS_AS(wq + cur * 2048 + 512), 16, 0, 0);
    };
    f32x4 acc = {};
    stage(0, 0);
#pragma unroll 2
    for (int ks = 0; ks < 8; ++ks) {
      int cur = ks & 1;
      if (ks < 7) {
        stage(cur ^ 1, ks + 1);
        asm volatile("s_waitcnt vmcnt(2)" ::: "memory");
      } else {
        asm volatile("s_waitcnt vmcnt(0)" ::: "memory");
      }
      int pA = (ks * 4 + lc) ^ (lrow & 7);
      bf16x8 ah = *(const bf16x8*)(sH1 + lrow * 256 + pA * 8);
      bf16x8 al = *(const bf16x8*)(sH1 + 4096 + lrow * 256 + pA * 8);
      bf16x8 bh = *(const bf16x8*)(wq + cur * 2048 + lane * 8);
      bf16x8 bl = *(const bf16x8*)(wq + cur * 2048 + 512 + lane * 8);
      MF3(ah, al, bh, bl, acc);
    }
    int col = wid * 16 + lrow;
    float bv = b2[col];
    int kc = col >> 3, wi = col & 7;
#pragma unroll
    for (int rr = 0; rr < 4; ++rr) {
      int r = lc * 4 + rr;
      float v = fmaxf(acc[rr] + bv, 0.f);
      ushort_t h = f2bf(v);
      int byo = r * 256 + ((kc ^ (r & 7)) * 8 + wi) * 2;
      *(ushort_t*)((char*)sH2 + byo) = h;
      *(ushort_t*)((char*)sH2 + 4096 + byo) = f2bf(v - bf2f(h));
    }
  }
  __syncthreads();

  // ================= phase D: GEMM3 (N=1024, K=128) + sigmoid =============
  {
    auto stage = [&](int cur, int u) {  // u = ks*4 + cp
      int ks = u >> 2, cp = u & 3;
#pragma unroll
      for (int j = 0; j < 2; ++j) {
        int col = wid * 128 + cp * 32 + j * 16 + lrow;
        const ushort_t* s0 = w3h + (size_t)col * 128 + ks * 32 + lc * 8;
        const ushort_t* s1 = w3l + (size_t)col * 128 + ks * 32 + lc * 8;
        __builtin_amdgcn_global_load_lds(GLOBAL_AS(s0),
            LDS_AS(wq + cur * 2048 + j * 1024), 16, 0, 0);
        __builtin_amdgcn_global_load_lds(GLOBAL_AS(s1),
            LDS_AS(wq + cur * 2048 + j * 1024 + 512), 16, 0, 0);
      }
    };
    f32x4 acc[8] = {};
    bf16x8 ah = {}, al = {};
    stage(0, 0);
#pragma unroll
    for (int u = 0; u < 16; ++u) {
      int cur = u & 1, ks = u >> 2, cp = u & 3;
      if (u < 15) {
        stage(cur ^ 1, u + 1);
        asm volatile("s_waitcnt vmcnt(4)" ::: "memory");
      } else {
        asm volatile("s_waitcnt vmcnt(0)" ::: "memory");
      }
      if (cp == 0) {
        int pA = (ks * 4 + lc) ^ (lrow & 7);
        ah = *(const bf16x8*)(sH2 + lrow * 128 + pA * 8);
        al = *(const bf16x8*)(sH2 + 2048 + lrow * 128 + pA * 8);
      }
      bf16x8 b0h = *(const bf16x8*)(wq + cur * 2048 + lane * 8);
      bf16x8 b0l = *(const bf16x8*)(wq + cur * 2048 + 512 + lane * 8);
      bf16x8 b1h = *(const bf16x8*)(wq + cur * 2048 + 1024 + lane * 8);
      bf16x8 b1l = *(const bf16x8*)(wq + cur * 2048 + 1536 + lane * 8);
      MF3(ah, al, b0h, b0l, acc[cp * 2 + 0]);
      MF3(ah, al, b1h, b1l, acc[cp * 2 + 1]);
    }
#pragma unroll
    for (int cp = 0; cp < 4; ++cp)
#pragma unroll
      for (int j = 0; j < 2; ++j) {
        int col = wid * 128 + cp * 32 + j * 16 + lrow;
        float bv = b3[col];
#pragma unroll
        for (int rr = 0; rr < 4; ++rr) {
          int row = row0 + lc * 4 + rr;
          float v = acc[cp * 2 + j][rr] + bv;
          out[(size_t)row * N_OUT + col] = 1.f / (1.f + expf(-v));
        }
      }
  }
}

// ---------------------------------------------------------------------------
extern "C" void kernel_launch(void* const* d_in, const int* in_sizes, int n_in,
                              void* d_out, int out_size, void* d_ws,
                              size_t ws_size, hipStream_t stream) {
  const int* stu_id = (const int*)d_in[0];
  const int* q_idx = (const int*)d_in[3];
  const float* emb = (const float*)d_in[4];
  const float* fm_vars = (const float*)d_in[5];
  const float* w1 = (const float*)d_in[6];
  const float* b1 = (const float*)d_in[7];
  const float* w2 = (const float*)d_in[8];
  const float* b2 = (const float*)d_in[9];
  const float* w3 = (const float*)d_in[10];
  const float* b3 = (const float*)d_in[11];
  float* out = (float*)d_out;

  char* ws = (char*)d_ws;
  size_t off = 0;
  auto alloc = [&](size_t bytes) {
    void* p = ws + off;
    off += (bytes + 255) & ~(size_t)255;
    return p;
  };
  ushort_t* w1h = (ushort_t*)alloc(256 * N_OUT * 2);
  ushort_t* w1l = (ushort_t*)alloc(256 * N_OUT * 2);
  ushort_t* w2h = (ushort_t*)alloc(128 * 256 * 2);
  ushort_t* w2l = (ushort_t*)alloc(128 * 256 * 2);
  ushort_t* w3h = (ushort_t*)alloc(N_OUT * 128 * 2);
  ushort_t* w3l = (ushort_t*)alloc(N_OUT * 128 * 2);

  (void)hipFuncSetAttribute((const void*)cicdm_fused,
                            hipFuncAttributeMaxDynamicSharedMemorySize,
                            SMEM_BYTES);

  cicdm_split<<<832, 512, 0, stream>>>(w1, w2, w3, w1h, w1l, w2h, w2l, w3h,
                                       w3l);
  cicdm_fused<<<256, 512, SMEM_BYTES, stream>>>(stu_id, q_idx, emb, fm_vars,
                                                b1, b2, b3, w1h, w1l, w2h, w2l,
                                                w3h, w3l, out);
}

// Round 10
// 120.023 us; speedup vs baseline: 1.2037x; 1.2037x over previous
//
#include <hip/hip_runtime.h>
#include <math.h>

#define K_N   30
#define N_OUT 1024
#define BB    4096
#define SMEM_BYTES 81920

typedef unsigned short ushort_t;
typedef __attribute__((ext_vector_type(8))) short bf16x8;
typedef __attribute__((ext_vector_type(4))) float f32x4;

#define MFMA(a, b, c) (c) = __builtin_amdgcn_mfma_f32_16x16x32_bf16((a), (b), (c), 0, 0, 0)

__device__ __forceinline__ ushort_t f2bf(float x) {
  union { float f; unsigned u; } a; a.f = x;
  unsigned r = a.u + 0x7FFFu + ((a.u >> 16) & 1u);
  return (ushort_t)(r >> 16);
}
__device__ __forceinline__ float bf2f(ushort_t h) {
  union { float f; unsigned u; } a; a.u = ((unsigned)h) << 16;
  return a.f;
}

__device__ __forceinline__ float choquet_one(float v0, float v1, float v2,
                                             float F0, float F1, float F2,
                                             float F3, float F4, float F5) {
  // stable descending argsort of (v0,v1,v2); ties -> lower index first
  bool c01 = v1 > v0, c02 = v2 > v0, c12 = v2 > v1;
  int r0 = (int)c01 + (int)c02;
  int r1 = (int)(!c01) + (int)c12;
  int p0 = (r0 == 0) ? 0 : ((r1 == 0) ? 1 : 2);
  int p1 = (r0 == 1) ? 0 : ((r1 == 1) ? 1 : 2);
  int p2 = 3 - p0 - p1;
  float sv0 = (p0 == 0) ? v0 : ((p0 == 1) ? v1 : v2);
  float sv1 = (p1 == 0) ? v0 : ((p1 == 1) ? v1 : v2);
  float sv2 = (p2 == 0) ? v0 : ((p2 == 1) ? v1 : v2);
  float fm0 = (p0 == 0) ? F0 : ((p0 == 1) ? F1 : F3);  // FM[2^p0-1]
  float fm1 = (p2 == 2) ? F2 : ((p2 == 1) ? F4 : F5);  // FM[2^p0+2^p1-1]
  return (sv0 - sv1) * fm0 + (sv1 - sv2) * fm1 + sv2;
}

// ---------------------------------------------------------------------------
// Launch 1: weight f32 -> bf16 hi/lo split + FRAGMENT-ORDER repack.
// Dest layout per 16-col group cg, 32-wide k-chunk kc, lane l (=lc*16+lrow),
// within-chunk wi: dst = (cg*KCHUNKS + kc)*512 + l*8 + wi, where the fragment
// holds w[cg*16 + (l&15)][kc*32 + (l>>4)*8 + wi]. One wave-load of 1KB at
// (cg,kc) then yields each lane's bf16x8 MFMA operand, fully coalesced.
// ---------------------------------------------------------------------------
__global__ __launch_bounds__(512) void cicdm_split(
    const float* __restrict__ w1, const float* __restrict__ w2,
    const float* __restrict__ w3, ushort_t* __restrict__ w1fh,
    ushort_t* __restrict__ w1fl, ushort_t* __restrict__ w2fh,
    ushort_t* __restrict__ w2fl, ushort_t* __restrict__ w3fh,
    ushort_t* __restrict__ w3fl) {
  int i = blockIdx.x * 512 + threadIdx.x;  // 832*512 = 425984 exactly
  float v;
  ushort_t *ph, *pl;
  int dst;
  if (i < 262144) {  // w1: [256][1024], 16 cgs x 32 kcs
    int c = i >> 10, k = i & 1023;
    v = w1[i];
    dst = ((c >> 4) * 32 + (k >> 5)) * 512 + (((k >> 3) & 3) * 16 + (c & 15)) * 8 + (k & 7);
    ph = w1fh; pl = w1fl;
  } else if (i < 294912) {  // w2: [128][256], 8 cgs x 8 kcs
    int i2 = i - 262144;
    int c = i2 >> 8, k = i2 & 255;
    v = w2[i2];
    dst = ((c >> 4) * 8 + (k >> 5)) * 512 + (((k >> 3) & 3) * 16 + (c & 15)) * 8 + (k & 7);
    ph = w2fh; pl = w2fl;
  } else {  // w3: [1024][128], 64 cgs x 4 kcs
    int i3 = i - 294912;
    int c = i3 >> 7, k = i3 & 127;
    v = w3[i3];
    dst = ((c >> 4) * 4 + (k >> 5)) * 512 + (((k >> 3) & 3) * 16 + (c & 15)) * 8 + (k & 7);
    ph = w3fh; pl = w3fl;
  }
  ushort_t h = f2bf(v);
  ph[dst] = h;
  pl[dst] = f2bf(v - bf2f(h));
}

// ---------------------------------------------------------------------------
// Launch 2: fully-fused row-local kernel. 256 blocks x 512 thr (8 waves),
// block owns rows [bid*16, bid*16+16). 3 block barriers, no grid sync.
// LDS (81920 B): sC [hi 32K | lo 32K] @0 (XOR-swz); sH1 [hi 8K | lo 8K]
// @65536; sSel @65536 (phase A only, aliases sH1); sH2 [hi 4K | lo 4K] @0
// (aliases dead sC after phase B).
// W-operands: fragment-ordered global -> VGPR, 4-deep software pipeline
// (fully unrolled => static reg indices), 2-chain split accumulators.
// Split-bf16: acc += ah*wh + ah*wl + al*wh  (~2^-17 rel err).
// ---------------------------------------------------------------------------
__global__ __launch_bounds__(512, 2) void cicdm_fused(
    const int* __restrict__ stu_id, const int* __restrict__ q_idx,
    const float* __restrict__ emb, const float* __restrict__ fm_vars,
    const float* __restrict__ b1, const float* __restrict__ b2,
    const float* __restrict__ b3, const ushort_t* __restrict__ w1fh,
    const ushort_t* __restrict__ w1fl, const ushort_t* __restrict__ w2fh,
    const ushort_t* __restrict__ w2fl, const ushort_t* __restrict__ w3fh,
    const ushort_t* __restrict__ w3fl, float* __restrict__ out) {
  extern __shared__ __align__(16) char dsm[];
  ushort_t* sC = (ushort_t*)dsm;               // hi @0, lo @+16384 (ushorts)
  float* sSel = (float*)(dsm + 65536);
  ushort_t* sH1 = (ushort_t*)(dsm + 65536);    // hi @0, lo @+4096 (ushorts)
  ushort_t* sH2 = (ushort_t*)dsm;              // hi @0, lo @+2048 (ushorts)

  const int bid = blockIdx.x, tid = threadIdx.x;
  const int lane = tid & 63, wid = tid >> 6;
  const int lrow = lane & 15, lc = lane >> 4;
  const int row0 = bid * 16;

  // ================= phase A: choquet -> sC =================
  if (tid < 16 * K_N) {
    int r = tid / K_N, c = tid % K_N;
    float x = emb[(size_t)stu_id[row0 + r] * K_N + c];
    sSel[r * 32 + c] = 1.f / (1.f + expf(-x));
  }
  __syncthreads();
  {
    const int n0 = tid * 2;
    const int qa0 = q_idx[n0 * 3 + 0], qa1 = q_idx[n0 * 3 + 1],
              qa2 = q_idx[n0 * 3 + 2];
    const int qb0 = q_idx[n0 * 3 + 3], qb1 = q_idx[n0 * 3 + 4],
              qb2 = q_idx[n0 * 3 + 5];
    float fa[6], fb[6];
#pragma unroll
    for (int v = 0; v < 6; ++v) {
      fa[v] = fabsf(fm_vars[v * N_OUT + n0]);
      fb[v] = fabsf(fm_vars[v * N_OUT + n0 + 1]);
    }
    float A0 = fminf(fa[0], 1.f), A1 = fminf(fa[1], 1.f), A3 = fminf(fa[3], 1.f);
    float A2 = fminf(fmaxf(fa[0], fa[1]) + fa[2], 1.f);
    float A4 = fminf(fmaxf(fa[3], fa[0]) + fa[4], 1.f);
    float A5 = fminf(fmaxf(fa[3], fa[1]) + fa[5], 1.f);
    float B0 = fminf(fb[0], 1.f), B1 = fminf(fb[1], 1.f), B3 = fminf(fb[3], 1.f);
    float B2 = fminf(fmaxf(fb[0], fb[1]) + fb[2], 1.f);
    float B4 = fminf(fmaxf(fb[3], fb[0]) + fb[4], 1.f);
    float B5 = fminf(fmaxf(fb[3], fb[1]) + fb[5], 1.f);
    const int kc = n0 >> 3, wi = n0 & 7;
#pragma unroll 4
    for (int r = 0; r < 16; ++r) {
      const float* sr = sSel + r * 32;
      float cA = choquet_one(sr[qa0], sr[qa1], sr[qa2], A0, A1, A2, A3, A4, A5);
      float cB = choquet_one(sr[qb0], sr[qb1], sr[qb2], B0, B1, B2, B3, B4, B5);
      ushort_t hA = f2bf(cA), hB = f2bf(cB);
      ushort_t lA = f2bf(cA - bf2f(hA)), lB = f2bf(cB - bf2f(hB));
      int byo = r * 2048 + ((kc ^ (r & 7)) * 8 + wi) * 2;
      *(unsigned*)((char*)sC + byo) = (unsigned)hA | ((unsigned)hB << 16);
      *(unsigned*)((char*)sC + 32768 + byo) = (unsigned)lA | ((unsigned)lB << 16);
    }
  }
  __syncthreads();

  // ================= phase B: GEMM1 (N=256, K=1024) =================
  // wave handles cols [wid*32, wid*32+32) = 2 cgs; 64 micro-steps (kc,j).
  {
    const ushort_t* baseH = w1fh + wid * 32768 + lane * 8;
    const ushort_t* baseL = w1fl + wid * 32768 + lane * 8;
    bf16x8 ph[4], pl[4];
    f32x4 cA1 = {}, cA2 = {}, cB1 = {}, cB2 = {};
    bf16x8 ah = {}, al = {};
#define LD1(s, d)                                                   \
  do {                                                              \
    int o = (((s) & 1) * 16384) + (((s) >> 1) * 512);               \
    ph[d] = *(const bf16x8*)(baseH + o);                            \
    pl[d] = *(const bf16x8*)(baseL + o);                            \
  } while (0)
    LD1(0, 0); LD1(1, 1); LD1(2, 2); LD1(3, 3);
#pragma unroll
    for (int s = 0; s < 64; ++s) {
      int kc = s >> 1;
      if ((s & 1) == 0) {
        int pA = (kc * 4 + lc) ^ (lrow & 7);
        ah = *(const bf16x8*)(sC + lrow * 1024 + pA * 8);
        al = *(const bf16x8*)(sC + 16384 + lrow * 1024 + pA * 8);
      }
      bf16x8 wh = ph[s & 3], wl = pl[s & 3];
      if ((s & 1) == 0) {
        MFMA(ah, wh, cA1); MFMA(ah, wl, cA2); MFMA(al, wh, cA2);
      } else {
        MFMA(ah, wh, cB1); MFMA(ah, wl, cB2); MFMA(al, wh, cB2);
      }
      if (s + 4 < 64) LD1(s + 4, s & 3);
    }
#undef LD1
    f32x4 accs[2] = {cA1 + cA2, cB1 + cB2};
    // epilogue -> sH1 (relu, hi/lo, swizzled)
#pragma unroll
    for (int j = 0; j < 2; ++j) {
      int col = wid * 32 + j * 16 + lrow;
      float bv = b1[col];
      int kc2 = col >> 3, wi2 = col & 7;
#pragma unroll
      for (int rr = 0; rr < 4; ++rr) {
        int r = lc * 4 + rr;
        float v = fmaxf(accs[j][rr] + bv, 0.f);
        ushort_t h = f2bf(v);
        int byo = r * 512 + ((kc2 ^ (r & 7)) * 8 + wi2) * 2;
        *(ushort_t*)((char*)sH1 + byo) = h;
        *(ushort_t*)((char*)sH1 + 8192 + byo) = f2bf(v - bf2f(h));
      }
    }
  }
  __syncthreads();

  // ================= phase C: GEMM2 (N=128, K=256) =================
  // wave handles cols [wid*16, wid*16+16) = 1 cg; 8 micro-steps (kc).
  {
    const ushort_t* baseH = w2fh + wid * 4096 + lane * 8;
    const ushort_t* baseL = w2fl + wid * 4096 + lane * 8;
    bf16x8 ph[4], pl[4];
    f32x4 c1 = {}, c2 = {};
#define LD2(s, d)                                                   \
  do {                                                              \
    int o = (s) * 512;                                              \
    ph[d] = *(const bf16x8*)(baseH + o);                            \
    pl[d] = *(const bf16x8*)(baseL + o);                            \
  } while (0)
    LD2(0, 0); LD2(1, 1); LD2(2, 2); LD2(3, 3);
#pragma unroll
    for (int s = 0; s < 8; ++s) {
      int pA = (s * 4 + lc) ^ (lrow & 7);
      bf16x8 ah = *(const bf16x8*)(sH1 + lrow * 256 + pA * 8);
      bf16x8 al = *(const bf16x8*)(sH1 + 4096 + lrow * 256 + pA * 8);
      bf16x8 wh = ph[s & 3], wl = pl[s & 3];
      MFMA(ah, wh, c1); MFMA(ah, wl, c2); MFMA(al, wh, c2);
      if (s + 4 < 8) LD2(s + 4, s & 3);
    }
#undef LD2
    f32x4 acc = c1 + c2;
    int col = wid * 16 + lrow;
    float bv = b2[col];
    int kc2 = col >> 3, wi2 = col & 7;
#pragma unroll
    for (int rr = 0; rr < 4; ++rr) {
      int r = lc * 4 + rr;
      float v = fmaxf(acc[rr] + bv, 0.f);
      ushort_t h = f2bf(v);
      int byo = r * 256 + ((kc2 ^ (r & 7)) * 8 + wi2) * 2;
      *(ushort_t*)((char*)sH2 + byo) = h;
      *(ushort_t*)((char*)sH2 + 4096 + byo) = f2bf(v - bf2f(h));
    }
  }
  __syncthreads();

  // ================= phase D: GEMM3 (N=1024, K=128) + sigmoid =============
  // wave handles cols [wid*128, wid*128+128) = 8 cgs; 32 micro-steps (kc,cg).
  {
    const ushort_t* baseH = w3fh + wid * 16384 + lane * 8;
    const ushort_t* baseL = w3fl + wid * 16384 + lane * 8;
    bf16x8 ph[4], pl[4];
    f32x4 a1[8] = {}, a2[8] = {};
    bf16x8 ah = {}, al = {};
#define LD3(s, d)                                                   \
  do {                                                              \
    int o = (((s) & 7) * 2048) + (((s) >> 3) * 512);                \
    ph[d] = *(const bf16x8*)(baseH + o);                            \
    pl[d] = *(const bf16x8*)(baseL + o);                            \
  } while (0)
    LD3(0, 0); LD3(1, 1); LD3(2, 2); LD3(3, 3);
#pragma unroll
    for (int s = 0; s < 32; ++s) {
      int ks = s >> 3, cg = s & 7;
      if (cg == 0) {
        int pA = (ks * 4 + lc) ^ (lrow & 7);
        ah = *(const bf16x8*)(sH2 + lrow * 128 + pA * 8);
        al = *(const bf16x8*)(sH2 + 2048 + lrow * 128 + pA * 8);
      }
      bf16x8 wh = ph[s & 3], wl = pl[s & 3];
      MFMA(ah, wh, a1[cg]); MFMA(ah, wl, a2[cg]); MFMA(al, wh, a2[cg]);
      if (s + 4 < 32) LD3(s + 4, s & 3);
    }
#undef LD3
#pragma unroll
    for (int cg = 0; cg < 8; ++cg) {
      f32x4 acc = a1[cg] + a2[cg];
      int col = wid * 128 + cg * 16 + lrow;
      float bv = b3[col];
#pragma unroll
      for (int rr = 0; rr < 4; ++rr) {
        int row = row0 + lc * 4 + rr;
        float v = acc[rr] + bv;
        out[(size_t)row * N_OUT + col] = 1.f / (1.f + expf(-v));
      }
    }
  }
}

// ---------------------------------------------------------------------------
extern "C" void kernel_launch(void* const* d_in, const int* in_sizes, int n_in,
                              void* d_out, int out_size, void* d_ws,
                              size_t ws_size, hipStream_t stream) {
  const int* stu_id = (const int*)d_in[0];
  const int* q_idx = (const int*)d_in[3];
  const float* emb = (const float*)d_in[4];
  const float* fm_vars = (const float*)d_in[5];
  const float* w1 = (const float*)d_in[6];
  const float* b1 = (const float*)d_in[7];
  const float* w2 = (const float*)d_in[8];
  const float* b2 = (const float*)d_in[9];
  const float* w3 = (const float*)d_in[10];
  const float* b3 = (const float*)d_in[11];
  float* out = (float*)d_out;

  char* ws = (char*)d_ws;
  size_t off = 0;
  auto alloc = [&](size_t bytes) {
    void* p = ws + off;
    off += (bytes + 255) & ~(size_t)255;
    return p;
  };
  ushort_t* w1fh = (ushort_t*)alloc(256 * N_OUT * 2);
  ushort_t* w1fl = (ushort_t*)alloc(256 * N_OUT * 2);
  ushort_t* w2fh = (ushort_t*)alloc(128 * 256 * 2);
  ushort_t* w2fl = (ushort_t*)alloc(128 * 256 * 2);
  ushort_t* w3fh = (ushort_t*)alloc(N_OUT * 128 * 2);
  ushort_t* w3fl = (ushort_t*)alloc(N_OUT * 128 * 2);

  (void)hipFuncSetAttribute((const void*)cicdm_fused,
                            hipFuncAttributeMaxDynamicSharedMemorySize,
                            SMEM_BYTES);

  cicdm_split<<<832, 512, 0, stream>>>(w1, w2, w3, w1fh, w1fl, w2fh, w2fl,
                                       w3fh, w3fl);
  cicdm_fused<<<256, 512, SMEM_BYTES, stream>>>(stu_id, q_idx, emb, fm_vars,
                                                b1, b2, b3, w1fh, w1fl, w2fh,
                                                w2fl, w3fh, w3fl, out);
}

// Round 11
// 116.043 us; speedup vs baseline: 1.2450x; 1.0343x over previous
//
#include <hip/hip_runtime.h>
#include <math.h>

#define K_N   30
#define N_OUT 1024
#define BB    4096
#define SMEM_BYTES 81920

typedef unsigned short ushort_t;
typedef __attribute__((ext_vector_type(8))) short bf16x8;
typedef __attribute__((ext_vector_type(4))) float f32x4;

#define MFMA(a, b, c) (c) = __builtin_amdgcn_mfma_f32_16x16x32_bf16((a), (b), (c), 0, 0, 0)

__device__ __forceinline__ ushort_t f2bf(float x) {
  union { float f; unsigned u; } a; a.f = x;
  unsigned r = a.u + 0x7FFFu + ((a.u >> 16) & 1u);
  return (ushort_t)(r >> 16);
}
__device__ __forceinline__ float bf2f(ushort_t h) {
  union { float f; unsigned u; } a; a.u = ((unsigned)h) << 16;
  return a.f;
}

__device__ __forceinline__ float choquet_one(float v0, float v1, float v2,
                                             float F0, float F1, float F2,
                                             float F3, float F4, float F5) {
  // stable descending argsort of (v0,v1,v2); ties -> lower index first
  bool c01 = v1 > v0, c02 = v2 > v0, c12 = v2 > v1;
  int r0 = (int)c01 + (int)c02;
  int r1 = (int)(!c01) + (int)c12;
  int p0 = (r0 == 0) ? 0 : ((r1 == 0) ? 1 : 2);
  int p1 = (r0 == 1) ? 0 : ((r1 == 1) ? 1 : 2);
  int p2 = 3 - p0 - p1;
  float sv0 = (p0 == 0) ? v0 : ((p0 == 1) ? v1 : v2);
  float sv1 = (p1 == 0) ? v0 : ((p1 == 1) ? v1 : v2);
  float sv2 = (p2 == 0) ? v0 : ((p2 == 1) ? v1 : v2);
  float fm0 = (p0 == 0) ? F0 : ((p0 == 1) ? F1 : F3);  // FM[2^p0-1]
  float fm1 = (p2 == 2) ? F2 : ((p2 == 1) ? F4 : F5);  // FM[2^p0+2^p1-1]
  return (sv0 - sv1) * fm0 + (sv1 - sv2) * fm1 + sv2;
}

// ---------------------------------------------------------------------------
// Launch 1: weight f32 -> bf16 hi/lo split + FRAGMENT-ORDER repack.
// dst = (cg*KCHUNKS + kc)*512 + lane*8 + wi; fragment holds
// w[cg*16 + (lane&15)][kc*32 + (lane>>4)*8 + wi].
// ---------------------------------------------------------------------------
__global__ __launch_bounds__(512) void cicdm_split(
    const float* __restrict__ w1, const float* __restrict__ w2,
    const float* __restrict__ w3, ushort_t* __restrict__ w1fh,
    ushort_t* __restrict__ w1fl, ushort_t* __restrict__ w2fh,
    ushort_t* __restrict__ w2fl, ushort_t* __restrict__ w3fh,
    ushort_t* __restrict__ w3fl) {
  int i = blockIdx.x * 512 + threadIdx.x;  // 832*512 = 425984 exactly
  float v;
  ushort_t *ph, *pl;
  int dst;
  if (i < 262144) {  // w1: [256][1024], 16 cgs x 32 kcs
    int c = i >> 10, k = i & 1023;
    v = w1[i];
    dst = ((c >> 4) * 32 + (k >> 5)) * 512 + (((k >> 3) & 3) * 16 + (c & 15)) * 8 + (k & 7);
    ph = w1fh; pl = w1fl;
  } else if (i < 294912) {  // w2: [128][256], 8 cgs x 8 kcs
    int i2 = i - 262144;
    int c = i2 >> 8, k = i2 & 255;
    v = w2[i2];
    dst = ((c >> 4) * 8 + (k >> 5)) * 512 + (((k >> 3) & 3) * 16 + (c & 15)) * 8 + (k & 7);
    ph = w2fh; pl = w2fl;
  } else {  // w3: [1024][128], 64 cgs x 4 kcs
    int i3 = i - 294912;
    int c = i3 >> 7, k = i3 & 127;
    v = w3[i3];
    dst = ((c >> 4) * 4 + (k >> 5)) * 512 + (((k >> 3) & 3) * 16 + (c & 15)) * 8 + (k & 7);
    ph = w3fh; pl = w3fl;
  }
  ushort_t h = f2bf(v);
  ph[dst] = h;
  pl[dst] = f2bf(v - bf2f(h));
}

// ---------------------------------------------------------------------------
// Launch 2: fused row-local kernel. 256 blocks x 512 thr (8 waves/CU),
// block owns rows [bid*16, bid*16+16). 8-deep reg pipeline for weights,
// cross-phase prologues, A-operand ds_read prefetch (2-slot rotation).
// LDS (81920 B): sC hi/lo @0 (64K, XOR-swz); sH1 hi/lo @65536 (16K, aliases
// sSel); sH2 hi/lo @0 (aliases dead sC after phase B).
// Split-bf16: acc += ah*wh + ah*wl + al*wh  (~2^-17 rel err).
// ---------------------------------------------------------------------------
__global__ __launch_bounds__(512, 2) void cicdm_fused(
    const int* __restrict__ stu_id, const int* __restrict__ q_idx,
    const float* __restrict__ emb, const float* __restrict__ fm_vars,
    const float* __restrict__ b1, const float* __restrict__ b2,
    const float* __restrict__ b3, const ushort_t* __restrict__ w1fh,
    const ushort_t* __restrict__ w1fl, const ushort_t* __restrict__ w2fh,
    const ushort_t* __restrict__ w2fl, const ushort_t* __restrict__ w3fh,
    const ushort_t* __restrict__ w3fl, float* __restrict__ out) {
  extern __shared__ __align__(16) char dsm[];
  ushort_t* sC = (ushort_t*)dsm;               // hi @0, lo @+16384 (ushorts)
  float* sSel = (float*)(dsm + 65536);
  ushort_t* sH1 = (ushort_t*)(dsm + 65536);    // hi @0, lo @+4096 (ushorts)
  ushort_t* sH2 = (ushort_t*)dsm;              // hi @0, lo @+2048 (ushorts)

  const int bid = blockIdx.x, tid = threadIdx.x;
  const int lane = tid & 63, wid = tid >> 6;
  const int lrow = lane & 15, lc = lane >> 4;
  const int row0 = bid * 16;
  const int sw = lrow & 7;

  const ushort_t* w1H = w1fh + wid * 32768 + lane * 8;
  const ushort_t* w1L = w1fl + wid * 32768 + lane * 8;
  const ushort_t* w2H = w2fh + wid * 4096 + lane * 8;
  const ushort_t* w2L = w2fl + wid * 4096 + lane * 8;
  const ushort_t* w3H = w3fh + wid * 16384 + lane * 8;
  const ushort_t* w3L = w3fl + wid * 16384 + lane * 8;

  bf16x8 ph[8], pl[8];  // shared 8-deep weight pipeline across phases

#define LD1(s, d)                                             \
  do {                                                        \
    int o = (((s) & 1) * 16384) + (((s) >> 1) * 512);         \
    ph[d] = *(const bf16x8*)(w1H + o);                        \
    pl[d] = *(const bf16x8*)(w1L + o);                        \
  } while (0)
#define LD2(s, d)                                             \
  do {                                                        \
    int o = (s) * 512;                                        \
    ph[d] = *(const bf16x8*)(w2H + o);                        \
    pl[d] = *(const bf16x8*)(w2L + o);                        \
  } while (0)
#define LD3(s, d)                                             \
  do {                                                        \
    int o = (((s) & 7) * 2048) + (((s) >> 3) * 512);          \
    ph[d] = *(const bf16x8*)(w3H + o);                        \
    pl[d] = *(const bf16x8*)(w3L + o);                        \
  } while (0)

  // ---- phase B prologue issued FIRST (hides L2 latency under phase A) ----
  LD1(0, 0); LD1(1, 1); LD1(2, 2); LD1(3, 3);
  LD1(4, 4); LD1(5, 5); LD1(6, 6); LD1(7, 7);

  // ================= phase A: choquet -> sC =================
  if (tid < 16 * K_N) {
    int r = tid / K_N, c = tid % K_N;
    float x = emb[(size_t)stu_id[row0 + r] * K_N + c];
    sSel[r * 32 + c] = 1.f / (1.f + expf(-x));
  }
  __syncthreads();
  {
    const int n0 = tid * 2;
    const int qa0 = q_idx[n0 * 3 + 0], qa1 = q_idx[n0 * 3 + 1],
              qa2 = q_idx[n0 * 3 + 2];
    const int qb0 = q_idx[n0 * 3 + 3], qb1 = q_idx[n0 * 3 + 4],
              qb2 = q_idx[n0 * 3 + 5];
    float fa[6], fb[6];
#pragma unroll
    for (int v = 0; v < 6; ++v) {
      fa[v] = fabsf(fm_vars[v * N_OUT + n0]);
      fb[v] = fabsf(fm_vars[v * N_OUT + n0 + 1]);
    }
    float A0 = fminf(fa[0], 1.f), A1 = fminf(fa[1], 1.f), A3 = fminf(fa[3], 1.f);
    float A2 = fminf(fmaxf(fa[0], fa[1]) + fa[2], 1.f);
    float A4 = fminf(fmaxf(fa[3], fa[0]) + fa[4], 1.f);
    float A5 = fminf(fmaxf(fa[3], fa[1]) + fa[5], 1.f);
    float B0 = fminf(fb[0], 1.f), B1 = fminf(fb[1], 1.f), B3 = fminf(fb[3], 1.f);
    float B2 = fminf(fmaxf(fb[0], fb[1]) + fb[2], 1.f);
    float B4 = fminf(fmaxf(fb[3], fb[0]) + fb[4], 1.f);
    float B5 = fminf(fmaxf(fb[3], fb[1]) + fb[5], 1.f);
    const int kc = n0 >> 3, wi = n0 & 7;
#pragma unroll 4
    for (int r = 0; r < 16; ++r) {
      const float* sr = sSel + r * 32;
      float cA = choquet_one(sr[qa0], sr[qa1], sr[qa2], A0, A1, A2, A3, A4, A5);
      float cB = choquet_one(sr[qb0], sr[qb1], sr[qb2], B0, B1, B2, B3, B4, B5);
      ushort_t hA = f2bf(cA), hB = f2bf(cB);
      ushort_t lA = f2bf(cA - bf2f(hA)), lB = f2bf(cB - bf2f(hB));
      int byo = r * 2048 + ((kc ^ (r & 7)) * 8 + wi) * 2;
      *(unsigned*)((char*)sC + byo) = (unsigned)hA | ((unsigned)hB << 16);
      *(unsigned*)((char*)sC + 32768 + byo) = (unsigned)lA | ((unsigned)lB << 16);
    }
  }
  __syncthreads();

  // ================= phase B: GEMM1 (N=256, K=1024) =================
  {
    f32x4 cA1 = {}, cA2 = {}, cB1 = {}, cB2 = {};
    bf16x8 aH[2], aL[2];
    {
      int pA = lc ^ sw;
      aH[0] = *(const bf16x8*)(sC + lrow * 1024 + pA * 8);
      aL[0] = *(const bf16x8*)(sC + 16384 + lrow * 1024 + pA * 8);
    }
#pragma unroll
    for (int s = 0; s < 64; ++s) {
      int kc = s >> 1;
      if ((s & 1) == 0 && kc + 1 < 32) {  // prefetch next k-chunk from LDS
        int pA = ((kc + 1) * 4 + lc) ^ sw;
        aH[(kc + 1) & 1] = *(const bf16x8*)(sC + lrow * 1024 + pA * 8);
        aL[(kc + 1) & 1] = *(const bf16x8*)(sC + 16384 + lrow * 1024 + pA * 8);
      }
      bf16x8 wh = ph[s & 7], wl = pl[s & 7];
      bf16x8 ah = aH[kc & 1], al = aL[kc & 1];
      if ((s & 1) == 0) {
        MFMA(ah, wh, cA1); MFMA(ah, wl, cA2); MFMA(al, wh, cA2);
      } else {
        MFMA(ah, wh, cB1); MFMA(ah, wl, cB2); MFMA(al, wh, cB2);
      }
      if (s + 8 < 64) LD1(s + 8, s & 7);
    }
    // phase C prologue (8 steps = whole phase) before epilogue
    LD2(0, 0); LD2(1, 1); LD2(2, 2); LD2(3, 3);
    LD2(4, 4); LD2(5, 5); LD2(6, 6); LD2(7, 7);
    f32x4 accs[2] = {cA1 + cA2, cB1 + cB2};
#pragma unroll
    for (int j = 0; j < 2; ++j) {
      int col = wid * 32 + j * 16 + lrow;
      float bv = b1[col];
      int kc2 = col >> 3, wi2 = col & 7;
#pragma unroll
      for (int rr = 0; rr < 4; ++rr) {
        int r = lc * 4 + rr;
        float v = fmaxf(accs[j][rr] + bv, 0.f);
        ushort_t h = f2bf(v);
        int byo = r * 512 + ((kc2 ^ (r & 7)) * 8 + wi2) * 2;
        *(ushort_t*)((char*)sH1 + byo) = h;
        *(ushort_t*)((char*)sH1 + 8192 + byo) = f2bf(v - bf2f(h));
      }
    }
  }
  __syncthreads();

  // ================= phase C: GEMM2 (N=128, K=256) =================
  {
    f32x4 c1 = {}, c2 = {};
    bf16x8 aH[2], aL[2];
    {
      int pA = lc ^ sw;
      aH[0] = *(const bf16x8*)(sH1 + lrow * 256 + pA * 8);
      aL[0] = *(const bf16x8*)(sH1 + 4096 + lrow * 256 + pA * 8);
    }
#pragma unroll
    for (int s = 0; s < 8; ++s) {
      if (s + 1 < 8) {
        int pA = ((s + 1) * 4 + lc) ^ sw;
        aH[(s + 1) & 1] = *(const bf16x8*)(sH1 + lrow * 256 + pA * 8);
        aL[(s + 1) & 1] = *(const bf16x8*)(sH1 + 4096 + lrow * 256 + pA * 8);
      }
      MFMA(aH[s & 1], ph[s & 7], c1);
      MFMA(aH[s & 1], pl[s & 7], c2);
      MFMA(aL[s & 1], ph[s & 7], c2);
    }
    // phase D prologue before epilogue
    LD3(0, 0); LD3(1, 1); LD3(2, 2); LD3(3, 3);
    LD3(4, 4); LD3(5, 5); LD3(6, 6); LD3(7, 7);
    f32x4 acc = c1 + c2;
    int col = wid * 16 + lrow;
    float bv = b2[col];
    int kc2 = col >> 3, wi2 = col & 7;
#pragma unroll
    for (int rr = 0; rr < 4; ++rr) {
      int r = lc * 4 + rr;
      float v = fmaxf(acc[rr] + bv, 0.f);
      ushort_t h = f2bf(v);
      int byo = r * 256 + ((kc2 ^ (r & 7)) * 8 + wi2) * 2;
      *(ushort_t*)((char*)sH2 + byo) = h;
      *(ushort_t*)((char*)sH2 + 4096 + byo) = f2bf(v - bf2f(h));
    }
  }
  __syncthreads();

  // ================= phase D: GEMM3 (N=1024, K=128) + sigmoid =============
  {
    f32x4 a1[8] = {}, a2[8] = {};
    bf16x8 aH[2], aL[2];
    {
      int pA = lc ^ sw;
      aH[0] = *(const bf16x8*)(sH2 + lrow * 128 + pA * 8);
      aL[0] = *(const bf16x8*)(sH2 + 2048 + lrow * 128 + pA * 8);
    }
#pragma unroll
    for (int s = 0; s < 32; ++s) {
      int ks = s >> 3, cg = s & 7;
      if (cg == 0 && ks + 1 < 4) {
        int pA = ((ks + 1) * 4 + lc) ^ sw;
        aH[(ks + 1) & 1] = *(const bf16x8*)(sH2 + lrow * 128 + pA * 8);
        aL[(ks + 1) & 1] = *(const bf16x8*)(sH2 + 2048 + lrow * 128 + pA * 8);
      }
      MFMA(aH[ks & 1], ph[s & 7], a1[cg]);
      MFMA(aH[ks & 1], pl[s & 7], a2[cg]);
      MFMA(aL[ks & 1], ph[s & 7], a2[cg]);
      if (s + 8 < 32) LD3(s + 8, s & 7);
    }
#pragma unroll
    for (int cg = 0; cg < 8; ++cg) {
      f32x4 acc = a1[cg] + a2[cg];
      int col = wid * 128 + cg * 16 + lrow;
      float bv = b3[col];
#pragma unroll
      for (int rr = 0; rr < 4; ++rr) {
        int row = row0 + lc * 4 + rr;
        float v = acc[rr] + bv;
        out[(size_t)row * N_OUT + col] = 1.f / (1.f + expf(-v));
      }
    }
  }
#undef LD1
#undef LD2
#undef LD3
}

// ---------------------------------------------------------------------------
extern "C" void kernel_launch(void* const* d_in, const int* in_sizes, int n_in,
                              void* d_out, int out_size, void* d_ws,
                              size_t ws_size, hipStream_t stream) {
  const int* stu_id = (const int*)d_in[0];
  const int* q_idx = (const int*)d_in[3];
  const float* emb = (const float*)d_in[4];
  const float* fm_vars = (const float*)d_in[5];
  const float* w1 = (const float*)d_in[6];
  const float* b1 = (const float*)d_in[7];
  const float* w2 = (const float*)d_in[8];
  const float* b2 = (const float*)d_in[9];
  const float* w3 = (const float*)d_in[10];
  const float* b3 = (const float*)d_in[11];
  float* out = (float*)d_out;

  char* ws = (char*)d_ws;
  size_t off = 0;
  auto alloc = [&](size_t bytes) {
    void* p = ws + off;
    off += (bytes + 255) & ~(size_t)255;
    return p;
  };
  ushort_t* w1fh = (ushort_t*)alloc(256 * N_OUT * 2);
  ushort_t* w1fl = (ushort_t*)alloc(256 * N_OUT * 2);
  ushort_t* w2fh = (ushort_t*)alloc(128 * 256 * 2);
  ushort_t* w2fl = (ushort_t*)alloc(128 * 256 * 2);
  ushort_t* w3fh = (ushort_t*)alloc(N_OUT * 128 * 2);
  ushort_t* w3fl = (ushort_t*)alloc(N_OUT * 128 * 2);

  (void)hipFuncSetAttribute((const void*)cicdm_fused,
                            hipFuncAttributeMaxDynamicSharedMemorySize,
                            SMEM_BYTES);

  cicdm_split<<<832, 512, 0, stream>>>(w1, w2, w3, w1fh, w1fl, w2fh, w2fl,
                                       w3fh, w3fl);
  cicdm_fused<<<256, 512, SMEM_BYTES, stream>>>(stu_id, q_idx, emb, fm_vars,
                                                b1, b2, b3, w1fh, w1fl, w2fh,
                                                w2fl, w3fh, w3fl, out);
}